// Round 3
// baseline (406.090 us; speedup 1.0000x reference)
//
#include <hip/hip_runtime.h>

// ---------------------------------------------------------------------------
// HypothesisDecoder: dense-grid trilinear interp + fused fp16-MFMA conv stack
// Round 3: occupancy fix — PT=8, wave = 8 m-tiles x 1 col-tile (B reuse 8x),
// 38.4 KB LDS -> 4 blocks/CU, launch_bounds(256,4), 2-way-max LDS patterns.
// ---------------------------------------------------------------------------
#define GG 96
#define NB 2
#define RESV 0.04f

constexpr int NG  = NB * GG * GG * GG;  // dense voxel grid cells (1,769,472)
constexpr int PT  = 8;                  // points per block
constexpr int NCOLS = PT * 8;           // 64 output columns (7 real + 1 dead per pt)
constexpr int XC  = NCOLS + 2;          // 66 LDS columns
constexpr int CS  = 136;                // LDS stride in halves (272B = 68 dwords)

typedef _Float16 f16x8 __attribute__((ext_vector_type(8)));
typedef _Float16 f16x4 __attribute__((ext_vector_type(4)));
typedef _Float16 f16x2 __attribute__((ext_vector_type(2)));
typedef float    f32x4 __attribute__((ext_vector_type(4)));

// ---------------------------------------------------------------------------
__global__ void k_init(int4* __restrict__ grid4, int* __restrict__ minc) {
    int i = blockIdx.x * 256 + threadIdx.x;
    if (i < NG / 4) grid4[i] = make_int4(0x7fffffff, 0x7fffffff, 0x7fffffff, 0x7fffffff);
    if (i < 6)      minc[i] = 0x7fffffff;
}

__global__ void k_scatter(const int* __restrict__ coords, const int* __restrict__ sbatch,
                          int n, int* __restrict__ grid, int* __restrict__ minc) {
    __shared__ int lmin[6];
    int tid = threadIdx.x;
    if (tid < 6) lmin[tid] = 0x7fffffff;
    __syncthreads();
    int i = blockIdx.x * 256 + tid;
    if (i < n) {
        int cx = coords[3*i], cy = coords[3*i+1], cz = coords[3*i+2];
        int b = sbatch[i];
        // stable-argsort + leftmost searchsorted == keep smallest original index
        atomicMin(&grid[((b*GG + cx)*GG + cy)*GG + cz], i);
        atomicMin(&lmin[b*3+0], cx);
        atomicMin(&lmin[b*3+1], cy);
        atomicMin(&lmin[b*3+2], cz);
    }
    __syncthreads();
    if (tid < 6) atomicMin(&minc[tid], lmin[tid]);
}

// ---------------------------------------------------------------------------
// Weights -> fp16 MFMA-fragment order with BN scale folded in.
// Fragment index: (((mt*KS + ks)*64 + lane)*8 + j) ; element:
//   row = mt*16 + (lane&15), k = ks*32 + (lane>>4)*8 + j, tap = k/CIN, c = k%CIN
// tvec[layer*128 + ch] = b - m * (g / sqrt(v + eps))
__global__ void k_wconv(const float* __restrict__ w1, const float* __restrict__ w2,
                        const float* __restrict__ w3,
                        const float* __restrict__ g1, const float* __restrict__ b1,
                        const float* __restrict__ m1, const float* __restrict__ v1,
                        const float* __restrict__ g2, const float* __restrict__ b2,
                        const float* __restrict__ m2, const float* __restrict__ v2,
                        const float* __restrict__ g3, const float* __restrict__ b3,
                        const float* __restrict__ m3, const float* __restrict__ v3,
                        _Float16* __restrict__ o1, _Float16* __restrict__ o2,
                        _Float16* __restrict__ o3, float* __restrict__ tvec) {
    int e = blockIdx.x * 256 + threadIdx.x;
    if (e < 24576) {                              // layer 1: 128 x 192, KS=6
        int j = e & 7, lane = (e >> 3) & 63, t2 = e >> 9;   // t2 in [0,48)
        int mt = t2 / 6, ks = t2 % 6;
        int row = mt * 16 + (lane & 15);
        int k = ks * 32 + ((lane >> 4) << 3) + j;
        int tap = k >> 6, c = k & 63;
        float s = g1[row] / sqrtf(v1[row] + 1e-5f);
        o1[e] = (_Float16)(w1[(row * 64 + c) * 3 + tap] * s);
    } else if (e < 122880) {                      // layers 2/3: 128 x 384, KS=12
        int u = e - 24576;
        int layer = u / 49152;
        u %= 49152;
        int j = u & 7, lane = (u >> 3) & 63, t2 = u >> 9;   // t2 in [0,96)
        int mt = t2 / 12, ks = t2 % 12;
        int row = mt * 16 + (lane & 15);
        int k = ks * 32 + ((lane >> 4) << 3) + j;
        int tap = k >> 7, c = k & 127;
        const float* w = layer ? w3 : w2;
        const float* g = layer ? g3 : g2;
        const float* v = layer ? v3 : v2;
        float s = g[row] / sqrtf(v[row] + 1e-5f);
        (layer ? o3 : o2)[u] = (_Float16)(w[(row * 128 + c) * 3 + tap] * s);
    } else if (e < 123264) {                      // tvec: 3 x 128
        int i = e - 122880;
        int layer = i >> 7, ch = i & 127;
        const float* g = layer == 0 ? g1 : (layer == 1 ? g2 : g3);
        const float* b = layer == 0 ? b1 : (layer == 1 ? b2 : b3);
        const float* m = layer == 0 ? m1 : (layer == 1 ? m2 : m3);
        const float* v = layer == 0 ? v1 : (layer == 1 ? v2 : v3);
        float s = g[ch] / sqrtf(v[ch] + 1e-5f);
        tvec[i] = b[ch] - m[ch] * s;
    }
}

// ---------------------------------------------------------------------------
// One conv layer: D[128][64cols] = Wfold[128][3*CIN] * X_im2col + t, ReLU.
// Wave w owns col-tile w (16 cols), ALL 8 m-tiles. Per k-step: 1 B-load (LDS)
// feeds 8 MFMA (B reuse 8x); A fragments stream from global (L2-resident).
template<int CIN, int KS>
__device__ __forceinline__ void conv_layer(
    const _Float16* xin, const _Float16* __restrict__ wg,
    const float* tvl, _Float16* hout, int tid)
{
    const int wave = tid >> 6;
    const int lane = tid & 63;
    const int quad = lane >> 4;
    const int l15  = lane & 15;
    const int cb   = wave * 16;

    f32x4 acc[8] = {};

#pragma unroll
    for (int ks = 0; ks < KS; ++ks) {
        const int k0  = ks * 32 + quad * 8;
        const int tap = k0 / CIN;                 // CIN is 64/128 -> shifts
        const int c   = k0 & (CIN - 1);
        f16x8 Bf = *(const f16x8*)(xin + (cb + l15 + tap) * CS + c);
#pragma unroll
        for (int m = 0; m < 8; ++m) {
            f16x8 A = *(const f16x8*)(wg + (((m * KS + ks) * 64 + lane) << 3));
            acc[m] = __builtin_amdgcn_mfma_f32_16x16x32_f16(A, Bf, acc[m], 0, 0, 0);
        }
    }

    // epilogue: +bias(t), ReLU, cvt fp16, store. D: col=lane&15, row=quad*4+i
    if ((l15 & 7) != 7) {                         // skip dead cols (keep zeros)
        _Float16* dst = hout + (cb + l15 + 1) * CS + quad * 4;
#pragma unroll
        for (int m = 0; m < 8; ++m) {
            f32x4 tval = *(const f32x4*)(tvl + m * 16 + quad * 4);  // LDS bcast
            f16x4 o;
#pragma unroll
            for (int i = 0; i < 4; ++i)
                o[i] = (_Float16)fmaxf(acc[m][i] + tval[i], 0.f);
            *(f16x4*)(dst + m * 16) = o;
        }
    }
}

// ---------------------------------------------------------------------------
__global__ __launch_bounds__(256, 4) void k_main(
    const float* __restrict__ pdh, const float* __restrict__ ptsfeat,
    const int* __restrict__ pts_batch, const float* __restrict__ sfeats,
    const int* __restrict__ grid, const int* __restrict__ minc,
    const _Float16* __restrict__ w16_1, const _Float16* __restrict__ w16_2,
    const _Float16* __restrict__ w16_3, const float* __restrict__ tvec,
    const float* __restrict__ w4, const float* __restrict__ bias4,
    float* __restrict__ out, int N, int n_sp)
{
    __shared__ __align__(16) _Float16 hA[XC * CS];   // 17.95 KB
    __shared__ __align__(16) _Float16 hB[XC * CS];   // 17.95 KB
    __shared__ __align__(16) float    tv[384];
    __shared__ __align__(16) _Float16 w4h[384];
    __shared__ float lg[NCOLS];

    const int tid = threadIdx.x;
    const int p0  = blockIdx.x * PT;

    // stage BN bias + w4 (im2col order k = tap*128 + c)
    for (int e = tid; e < 384; e += 256) {
        tv[e]  = tvec[e];
        w4h[e] = (_Float16)w4[(e & 127) * 3 + (e >> 7)];
    }
    // zero only the 10 dead/pad columns (u = 0,8,...,64 and 65), both buffers
    for (int idx = tid; idx < 10 * (CS / 2); idx += 256) {
        int cidx = idx / (CS / 2), off = idx % (CS / 2);
        int u = (cidx < 9) ? cidx * 8 : 65;
        ((int*)hA)[u * (CS / 2) + off] = 0;
        ((int*)hB)[u * (CS / 2) + off] = 0;
    }

    // ---- trilinear interp + pts_feat staging: 56 queries x 4 ch-parts (8 ch)
    if (tid < 224) {
        int q = tid >> 2, part = tid & 3;
        int pl = q / 7, j = q - pl * 7;
        int pg = p0 + pl;
        if (pg < N) {
            int b = pts_batch[pg];
            const float* pd = pdh + ((size_t)pg * 7 + j) * 3;
            float qx = (pd[0] - (float)minc[b*3+0] * RESV) / RESV;
            float qy = (pd[1] - (float)minc[b*3+1] * RESV) / RESV;
            float qz = (pd[2] - (float)minc[b*3+2] * RESV) / RESV;
            float flx = floorf(qx), fly = floorf(qy), flz = floorf(qz);
            float fx = qx - flx, fy = qy - fly, fz = qz - flz;
            int ix0 = (int)flx, iy0 = (int)fly, iz0 = (int)flz;
            float acc[8];
#pragma unroll
            for (int k2 = 0; k2 < 8; ++k2) acc[k2] = 0.f;
#pragma unroll
            for (int dx = 0; dx < 2; ++dx) {
                int cx = ix0 + dx;
                if ((unsigned)cx >= GG) continue;
                float wx = dx ? fx : 1.f - fx;
#pragma unroll
                for (int dy = 0; dy < 2; ++dy) {
                    int cy = iy0 + dy;
                    if ((unsigned)cy >= GG) continue;
                    float wxy = wx * (dy ? fy : 1.f - fy);
                    int cellb = ((b * GG + cx) * GG + cy) * GG;
#pragma unroll
                    for (int dz = 0; dz < 2; ++dz) {
                        int cz = iz0 + dz;
                        if ((unsigned)cz >= GG) continue;
                        int si = grid[cellb + cz];
                        if (si < n_sp) {
                            float w = wxy * (dz ? fz : 1.f - fz);
                            const float4* fp = (const float4*)(sfeats + (size_t)si * 32 + part * 8);
                            float4 f0 = fp[0], f1 = fp[1];
                            acc[0] += w * f0.x; acc[1] += w * f0.y;
                            acc[2] += w * f0.z; acc[3] += w * f0.w;
                            acc[4] += w * f1.x; acc[5] += w * f1.y;
                            acc[6] += w * f1.z; acc[7] += w * f1.w;
                        }
                    }
                }
            }
            int u = pl * 8 + 1 + j;
            f16x8 hv, pv;
#pragma unroll
            for (int k2 = 0; k2 < 8; ++k2) hv[k2] = (_Float16)acc[k2];
            *(f16x8*)(hA + u * CS + part * 8) = hv;
            const float* pf = ptsfeat + ((size_t)pg * 7 + j) * 32 + part * 8;
#pragma unroll
            for (int k2 = 0; k2 < 8; ++k2) pv[k2] = (_Float16)pf[k2];
            *(f16x8*)(hA + u * CS + 32 + part * 8) = pv;
        }
    }
    __syncthreads();

    // ---- conv stack
    conv_layer<64,  6>(hA, w16_1, tv,       hB, tid);
    __syncthreads();
    conv_layer<128, 12>(hB, w16_2, tv + 128, hA, tid);
    __syncthreads();
    conv_layer<128, 12>(hA, w16_3, tv + 256, hB, tid);
    __syncthreads();

    // ---- layer 4: logits via packed dot2, 2 threads/col, interleaved chunks
    if (tid < 128) {
        int col = tid >> 1, part = tid & 1;
        float sum = 0.f;
        if ((col & 7) != 7) {
#pragma unroll
            for (int t = 0; t < 3; ++t) {
                const _Float16* hp = hB + (col + t) * CS;
                const _Float16* wr = w4h + t * 128;
#pragma unroll
                for (int c8 = 0; c8 < 8; ++c8) {
                    int chunk = 2 * c8 + part;            // bank-spread split
                    f16x8 h8 = *(const f16x8*)(hp + chunk * 8);
                    f16x8 w8 = *(const f16x8*)(wr + chunk * 8);
#pragma unroll
                    for (int p = 0; p < 4; ++p) {
                        f16x2 hv = { h8[2*p], h8[2*p+1] };
                        f16x2 wv = { w8[2*p], w8[2*p+1] };
#if __has_builtin(__builtin_amdgcn_fdot2)
                        sum = __builtin_amdgcn_fdot2(hv, wv, sum, false);
#else
                        sum += (float)hv[0]*(float)wv[0] + (float)hv[1]*(float)wv[1];
#endif
                    }
                }
            }
        }
        sum += __shfl_xor(sum, 1);
        if (part == 0 && (col & 7) != 7) lg[col] = sum + bias4[0];
    }
    __syncthreads();

    // ---- softmax over 7 hypotheses, one thread per point
    if (tid < PT) {
        int pg = p0 + tid;
        if (pg < N) {
            float l0[7];
            float mx = -1e30f;
#pragma unroll
            for (int j = 0; j < 7; ++j) { l0[j] = lg[tid * 8 + j]; mx = fmaxf(mx, l0[j]); }
            float s = 0.f;
#pragma unroll
            for (int j = 0; j < 7; ++j) { l0[j] = __expf(l0[j] - mx); s += l0[j]; }
            float inv = 1.f / s;
#pragma unroll
            for (int j = 0; j < 7; ++j) out[(size_t)pg * 7 + j] = l0[j] * inv;
        }
    }
}

// ---------------------------------------------------------------------------
extern "C" void kernel_launch(void* const* d_in, const int* in_sizes, int n_in,
                              void* d_out, int out_size, void* d_ws, size_t ws_size,
                              hipStream_t stream) {
    const int*   sparse_coords = (const int*)d_in[1];
    const int*   sparse_batch  = (const int*)d_in[2];
    const float* sparse_feats  = (const float*)d_in[3];
    const float* pdh           = (const float*)d_in[4];
    const float* ptsfeat       = (const float*)d_in[5];
    const int*   pts_batch     = (const int*)d_in[6];
    const float* w1 = (const float*)d_in[7];
    const float* g1 = (const float*)d_in[8],  *b1 = (const float*)d_in[9];
    const float* m1 = (const float*)d_in[10], *v1 = (const float*)d_in[11];
    const float* w2 = (const float*)d_in[12];
    const float* g2 = (const float*)d_in[13], *b2 = (const float*)d_in[14];
    const float* m2 = (const float*)d_in[15], *v2 = (const float*)d_in[16];
    const float* w3 = (const float*)d_in[17];
    const float* g3 = (const float*)d_in[18], *b3 = (const float*)d_in[19];
    const float* m3 = (const float*)d_in[20], *v3 = (const float*)d_in[21];
    const float* w4 = (const float*)d_in[22];
    const float* bias4 = (const float*)d_in[23];

    const int n_sp = in_sizes[2];
    const int N    = in_sizes[6];

    // workspace: [grid NG ints][minc 6][pad to 16B][w16_1|w16_2|w16_3][tvec]
    int* grid = (int*)d_ws;
    int* minc = grid + NG;
    _Float16* w16_1 = (_Float16*)((char*)d_ws + (size_t)(NG + 6) * 4 + 8);
    _Float16* w16_2 = w16_1 + 128 * 192;
    _Float16* w16_3 = w16_2 + 128 * 384;
    float*    tvec  = (float*)(w16_3 + 128 * 384);

    k_init<<<(NG / 4 + 255) / 256, 256, 0, stream>>>((int4*)grid, minc);
    k_scatter<<<(n_sp + 255) / 256, 256, 0, stream>>>(sparse_coords, sparse_batch,
                                                      n_sp, grid, minc);
    k_wconv<<<482, 256, 0, stream>>>(w1, w2, w3,
                                     g1, b1, m1, v1, g2, b2, m2, v2, g3, b3, m3, v3,
                                     w16_1, w16_2, w16_3, tvec);
    k_main<<<(N + PT - 1) / PT, 256, 0, stream>>>(
        pdh, ptsfeat, pts_batch, sparse_feats, grid, minc,
        w16_1, w16_2, w16_3, tvec, w4, bias4, (float*)d_out, N, n_sp);
}

// Round 4
// 304.997 us; speedup vs baseline: 1.3315x; 1.3315x over previous
//
#include <hip/hip_runtime.h>

// ---------------------------------------------------------------------------
// HypothesisDecoder: dense-grid trilinear interp + fused fp16-MFMA conv stack
// Round 4: round-2 structure (PT=16, 64ch x 64col wave tiles = balanced
// 0.5KB/MFMA operand traffic) + EXPLICIT software pipeline: A-fragments
// (global/L2) prefetched 3 k-steps ahead in rotating register buffers,
// B-fragments (LDS) 1 step ahead. r2/r3 were latency-bound on A (VGPR=60/104
// showed compiler did no prefetch); LDS caps us at 2 blocks/CU so VGPRs are free.
// ---------------------------------------------------------------------------
#define GG 96
#define NB 2
#define RESV 0.04f

constexpr int NG  = NB * GG * GG * GG;  // dense voxel grid cells (1,769,472)
constexpr int PT  = 16;                 // points per block
constexpr int NCOLS = PT * 8;           // 128 output columns (7 real + 1 dead per pt)
constexpr int XC  = NCOLS + 2;          // 130 LDS columns
constexpr int CS  = 136;                // LDS stride in halves (272B = 68 dwords)

typedef _Float16 f16x8 __attribute__((ext_vector_type(8)));
typedef _Float16 f16x4 __attribute__((ext_vector_type(4)));
typedef _Float16 f16x2 __attribute__((ext_vector_type(2)));
typedef float    f32x4 __attribute__((ext_vector_type(4)));

// ---------------------------------------------------------------------------
__global__ void k_init(int4* __restrict__ grid4, int* __restrict__ minc) {
    int i = blockIdx.x * 256 + threadIdx.x;
    if (i < NG / 4) grid4[i] = make_int4(0x7fffffff, 0x7fffffff, 0x7fffffff, 0x7fffffff);
    if (i < 6)      minc[i] = 0x7fffffff;
}

__global__ void k_scatter(const int* __restrict__ coords, const int* __restrict__ sbatch,
                          int n, int* __restrict__ grid, int* __restrict__ minc) {
    __shared__ int lmin[6];
    int tid = threadIdx.x;
    if (tid < 6) lmin[tid] = 0x7fffffff;
    __syncthreads();
    int i = blockIdx.x * 256 + tid;
    if (i < n) {
        int cx = coords[3*i], cy = coords[3*i+1], cz = coords[3*i+2];
        int b = sbatch[i];
        // stable-argsort + leftmost searchsorted == keep smallest original index
        atomicMin(&grid[((b*GG + cx)*GG + cy)*GG + cz], i);
        atomicMin(&lmin[b*3+0], cx);
        atomicMin(&lmin[b*3+1], cy);
        atomicMin(&lmin[b*3+2], cz);
    }
    __syncthreads();
    if (tid < 6) atomicMin(&minc[tid], lmin[tid]);
}

// ---------------------------------------------------------------------------
// Weights -> fp16 MFMA-fragment order with BN scale folded in.
// Fragment index: (((mt*KS + ks)*64 + lane)*8 + j) ; element:
//   row = mt*16 + (lane&15), k = ks*32 + (lane>>4)*8 + j, tap = k/CIN, c = k%CIN
// tvec[layer*128 + ch] = b - m * (g / sqrt(v + eps))
__global__ void k_wconv(const float* __restrict__ w1, const float* __restrict__ w2,
                        const float* __restrict__ w3,
                        const float* __restrict__ g1, const float* __restrict__ b1,
                        const float* __restrict__ m1, const float* __restrict__ v1,
                        const float* __restrict__ g2, const float* __restrict__ b2,
                        const float* __restrict__ m2, const float* __restrict__ v2,
                        const float* __restrict__ g3, const float* __restrict__ b3,
                        const float* __restrict__ m3, const float* __restrict__ v3,
                        _Float16* __restrict__ o1, _Float16* __restrict__ o2,
                        _Float16* __restrict__ o3, float* __restrict__ tvec) {
    int e = blockIdx.x * 256 + threadIdx.x;
    if (e < 24576) {                              // layer 1: 128 x 192, KS=6
        int j = e & 7, lane = (e >> 3) & 63, t2 = e >> 9;   // t2 in [0,48)
        int mt = t2 / 6, ks = t2 % 6;
        int row = mt * 16 + (lane & 15);
        int k = ks * 32 + ((lane >> 4) << 3) + j;
        int tap = k >> 6, c = k & 63;
        float s = g1[row] / sqrtf(v1[row] + 1e-5f);
        o1[e] = (_Float16)(w1[(row * 64 + c) * 3 + tap] * s);
    } else if (e < 122880) {                      // layers 2/3: 128 x 384, KS=12
        int u = e - 24576;
        int layer = u / 49152;
        u %= 49152;
        int j = u & 7, lane = (u >> 3) & 63, t2 = u >> 9;   // t2 in [0,96)
        int mt = t2 / 12, ks = t2 % 12;
        int row = mt * 16 + (lane & 15);
        int k = ks * 32 + ((lane >> 4) << 3) + j;
        int tap = k >> 7, c = k & 127;
        const float* w = layer ? w3 : w2;
        const float* g = layer ? g3 : g2;
        const float* v = layer ? v3 : v2;
        float s = g[row] / sqrtf(v[row] + 1e-5f);
        (layer ? o3 : o2)[u] = (_Float16)(w[(row * 128 + c) * 3 + tap] * s);
    } else if (e < 123264) {                      // tvec: 3 x 128
        int i = e - 122880;
        int layer = i >> 7, ch = i & 127;
        const float* g = layer == 0 ? g1 : (layer == 1 ? g2 : g3);
        const float* b = layer == 0 ? b1 : (layer == 1 ? b2 : b3);
        const float* m = layer == 0 ? m1 : (layer == 1 ? m2 : m3);
        const float* v = layer == 0 ? v1 : (layer == 1 ? v2 : v3);
        float s = g[ch] / sqrtf(v[ch] + 1e-5f);
        tvec[i] = b[ch] - m[ch] * s;
    }
}

// ---------------------------------------------------------------------------
// One conv layer: D[128][128cols] = Wfold[128][3*CIN] * X_im2col + t, ReLU.
// Wave w: channel-half mp=w&1 (m-tiles 4mp..4mp+3), col-half (w>>1)*64.
// Per k-step: 4 A (global, prefetched PF=3 ahead) + 4 B (LDS, 1 ahead)
// -> 16 MFMA. 64ch x 64col register tile = 0.5 KB operand per MFMA.
template<int CIN, int KS>
__device__ __forceinline__ void conv_layer(
    const _Float16* xin, const _Float16* __restrict__ wg,
    const float* tvl, _Float16* hout, int tid)
{
    const int wave = tid >> 6;
    const int lane = tid & 63;
    const int quad = lane >> 4;
    const int l15  = lane & 15;
    const int mp   = wave & 1;
    const int cb   = (wave >> 1) * 64;

    constexpr int PF = 3;                 // A prefetch depth (covers ~220cy L2)
    f32x4 acc[4][4] = {};
    f16x8 Abuf[PF][4];
    f16x8 Bbuf[2][4];

    const _Float16* wbase = wg + (((size_t)(mp * 4) * KS) * 64 + lane) * 8;

    auto loadA = [&](int slot, int ks) {
#pragma unroll
        for (int m = 0; m < 4; ++m)
            Abuf[slot][m] = *(const f16x8*)(wbase + (size_t)(m * KS + ks) * 512);
    };
    auto loadB = [&](int slot, int ks) {
        const int k0   = ks * 32 + quad * 8;
        const int tap  = k0 / CIN;        // CIN 64/128 -> shifts
        const int c    = k0 & (CIN - 1);
        const int boff = (cb + l15 + tap) * CS + c;
#pragma unroll
        for (int ct = 0; ct < 4; ++ct)
            Bbuf[slot][ct] = *(const f16x8*)(xin + boff + ct * 16 * CS);
    };

#pragma unroll
    for (int p = 0; p < PF; ++p) loadA(p, p);
    loadB(0, 0);

#pragma unroll
    for (int ks = 0; ks < KS; ++ks) {
        if (ks + 1 < KS) loadB((ks + 1) & 1, ks + 1);
#pragma unroll
        for (int ct = 0; ct < 4; ++ct)
#pragma unroll
            for (int m = 0; m < 4; ++m)
                acc[ct][m] = __builtin_amdgcn_mfma_f32_16x16x32_f16(
                    Abuf[ks % PF][m], Bbuf[ks & 1][ct], acc[ct][m], 0, 0, 0);
        if (ks + PF < KS) loadA(ks % PF, ks + PF);   // refill just-consumed slot
    }

    // epilogue: +bias(t), ReLU, cvt fp16, store. D: col=lane&15, row=quad*4+i
    if ((l15 & 7) != 7) {                 // skip dead columns (keep zeros zero)
#pragma unroll
        for (int ct = 0; ct < 4; ++ct) {
            const int outc = cb + ct * 16 + l15;
            _Float16* dst = hout + (outc + 1) * CS + mp * 64 + quad * 4;
#pragma unroll
            for (int m = 0; m < 4; ++m) {
                const int ch = mp * 64 + m * 16 + quad * 4;
                f32x4 tval = *(const f32x4*)(tvl + ch);   // LDS broadcast
                f16x4 o;
#pragma unroll
                for (int i = 0; i < 4; ++i)
                    o[i] = (_Float16)fmaxf(acc[ct][m][i] + tval[i], 0.f);
                *(f16x4*)(dst + m * 16) = o;
            }
        }
    }
}

// ---------------------------------------------------------------------------
__global__ __launch_bounds__(256, 2) void k_main(
    const float* __restrict__ pdh, const float* __restrict__ ptsfeat,
    const int* __restrict__ pts_batch, const float* __restrict__ sfeats,
    const int* __restrict__ grid, const int* __restrict__ minc,
    const _Float16* __restrict__ w16_1, const _Float16* __restrict__ w16_2,
    const _Float16* __restrict__ w16_3, const float* __restrict__ tvec,
    const float* __restrict__ w4, const float* __restrict__ bias4,
    float* __restrict__ out, int N, int n_sp)
{
    __shared__ __align__(16) _Float16 hA[XC * CS];
    __shared__ __align__(16) _Float16 hB[XC * CS];
    __shared__ __align__(16) float    tv[384];
    __shared__ __align__(16) _Float16 w4h[384];
    __shared__ float lg[NCOLS];

    const int tid = threadIdx.x;
    const int p0  = blockIdx.x * PT;

    // stage BN bias + w4 (im2col order k = tap*128 + c)
    for (int e = tid; e < 384; e += 256) {
        tv[e]  = tvec[e];
        w4h[e] = (_Float16)w4[(e & 127) * 3 + (e >> 7)];
    }
    // zero only the 18 dead/pad columns (u = 0,8,...,128 and 129), both buffers
    for (int idx = tid; idx < 18 * (CS / 2); idx += 256) {
        int cidx = idx / (CS / 2), off = idx % (CS / 2);
        int u = (cidx < 17) ? cidx * 8 : 129;
        ((int*)hA)[u * (CS / 2) + off] = 0;
        ((int*)hB)[u * (CS / 2) + off] = 0;
    }

    // ---- trilinear interp + pts_feat staging: 112 queries x 2 ch-parts
    if (tid < 224) {
        int q = tid >> 1, part = tid & 1;
        int pl = q / 7, j = q - pl * 7;
        int pg = p0 + pl;
        if (pg < N) {
            int b = pts_batch[pg];
            const float* pd = pdh + ((size_t)pg * 7 + j) * 3;
            float qx = (pd[0] - (float)minc[b*3+0] * RESV) / RESV;
            float qy = (pd[1] - (float)minc[b*3+1] * RESV) / RESV;
            float qz = (pd[2] - (float)minc[b*3+2] * RESV) / RESV;
            float flx = floorf(qx), fly = floorf(qy), flz = floorf(qz);
            float fx = qx - flx, fy = qy - fly, fz = qz - flz;
            int ix0 = (int)flx, iy0 = (int)fly, iz0 = (int)flz;
            float acc[16];
#pragma unroll
            for (int k2 = 0; k2 < 16; ++k2) acc[k2] = 0.f;
#pragma unroll
            for (int dx = 0; dx < 2; ++dx) {
                int cx = ix0 + dx;
                if ((unsigned)cx >= GG) continue;
                float wx = dx ? fx : 1.f - fx;
#pragma unroll
                for (int dy = 0; dy < 2; ++dy) {
                    int cy = iy0 + dy;
                    if ((unsigned)cy >= GG) continue;
                    float wxy = wx * (dy ? fy : 1.f - fy);
                    int cellb = ((b * GG + cx) * GG + cy) * GG;
#pragma unroll
                    for (int dz = 0; dz < 2; ++dz) {
                        int cz = iz0 + dz;
                        if ((unsigned)cz >= GG) continue;
                        int si = grid[cellb + cz];
                        if (si < n_sp) {
                            float w = wxy * (dz ? fz : 1.f - fz);
                            const float4* fp = (const float4*)(sfeats + (size_t)si * 32 + part * 16);
                            float4 f0 = fp[0], f1 = fp[1], f2 = fp[2], f3 = fp[3];
                            acc[0]  += w * f0.x; acc[1]  += w * f0.y;
                            acc[2]  += w * f0.z; acc[3]  += w * f0.w;
                            acc[4]  += w * f1.x; acc[5]  += w * f1.y;
                            acc[6]  += w * f1.z; acc[7]  += w * f1.w;
                            acc[8]  += w * f2.x; acc[9]  += w * f2.y;
                            acc[10] += w * f2.z; acc[11] += w * f2.w;
                            acc[12] += w * f3.x; acc[13] += w * f3.y;
                            acc[14] += w * f3.z; acc[15] += w * f3.w;
                        }
                    }
                }
            }
            int u = pl * 8 + 1 + j;
            _Float16* xp = hA + u * CS + part * 16;
            f16x8 h0, h1;
#pragma unroll
            for (int k2 = 0; k2 < 8; ++k2) { h0[k2] = (_Float16)acc[k2]; h1[k2] = (_Float16)acc[8 + k2]; }
            *(f16x8*)xp = h0;
            *(f16x8*)(xp + 8) = h1;
            const float* pf = ptsfeat + ((size_t)pg * 7 + j) * 32 + part * 16;
            f16x8 p0v, p1v;
#pragma unroll
            for (int k2 = 0; k2 < 8; ++k2) { p0v[k2] = (_Float16)pf[k2]; p1v[k2] = (_Float16)pf[8 + k2]; }
            *(f16x8*)(hA + u * CS + 32 + part * 16) = p0v;
            *(f16x8*)(hA + u * CS + 40 + part * 16) = p1v;
        }
    }
    __syncthreads();

    // ---- conv stack
    conv_layer<64,  6>(hA, w16_1, tv,       hB, tid);
    __syncthreads();
    conv_layer<128, 12>(hB, w16_2, tv + 128, hA, tid);
    __syncthreads();
    conv_layer<128, 12>(hA, w16_3, tv + 256, hB, tid);
    __syncthreads();

    // ---- layer 4: logits via packed dot2, 2 threads/col, interleaved chunks
    {
        int col = tid >> 1, part = tid & 1;
        float sum = 0.f;
        if ((col & 7) != 7) {
#pragma unroll
            for (int t = 0; t < 3; ++t) {
                const _Float16* hp = hB + (col + t) * CS;
                const _Float16* wr = w4h + t * 128;
#pragma unroll
                for (int c8 = 0; c8 < 8; ++c8) {
                    int chunk = 2 * c8 + part;            // bank-spread split
                    f16x8 h8 = *(const f16x8*)(hp + chunk * 8);
                    f16x8 w8 = *(const f16x8*)(wr + chunk * 8);
#pragma unroll
                    for (int p = 0; p < 4; ++p) {
                        f16x2 hv = { h8[2*p], h8[2*p+1] };
                        f16x2 wv = { w8[2*p], w8[2*p+1] };
#if __has_builtin(__builtin_amdgcn_fdot2)
                        sum = __builtin_amdgcn_fdot2(hv, wv, sum, false);
#else
                        sum += (float)hv[0]*(float)wv[0] + (float)hv[1]*(float)wv[1];
#endif
                    }
                }
            }
        }
        sum += __shfl_xor(sum, 1);
        if (part == 0 && (col & 7) != 7) lg[col] = sum + bias4[0];
    }
    __syncthreads();

    // ---- softmax over 7 hypotheses, one thread per point
    if (tid < PT) {
        int pg = p0 + tid;
        if (pg < N) {
            float l0[7];
            float mx = -1e30f;
#pragma unroll
            for (int j = 0; j < 7; ++j) { l0[j] = lg[tid * 8 + j]; mx = fmaxf(mx, l0[j]); }
            float s = 0.f;
#pragma unroll
            for (int j = 0; j < 7; ++j) { l0[j] = __expf(l0[j] - mx); s += l0[j]; }
            float inv = 1.f / s;
#pragma unroll
            for (int j = 0; j < 7; ++j) out[(size_t)pg * 7 + j] = l0[j] * inv;
        }
    }
}

// ---------------------------------------------------------------------------
extern "C" void kernel_launch(void* const* d_in, const int* in_sizes, int n_in,
                              void* d_out, int out_size, void* d_ws, size_t ws_size,
                              hipStream_t stream) {
    const int*   sparse_coords = (const int*)d_in[1];
    const int*   sparse_batch  = (const int*)d_in[2];
    const float* sparse_feats  = (const float*)d_in[3];
    const float* pdh           = (const float*)d_in[4];
    const float* ptsfeat       = (const float*)d_in[5];
    const int*   pts_batch     = (const int*)d_in[6];
    const float* w1 = (const float*)d_in[7];
    const float* g1 = (const float*)d_in[8],  *b1 = (const float*)d_in[9];
    const float* m1 = (const float*)d_in[10], *v1 = (const float*)d_in[11];
    const float* w2 = (const float*)d_in[12];
    const float* g2 = (const float*)d_in[13], *b2 = (const float*)d_in[14];
    const float* m2 = (const float*)d_in[15], *v2 = (const float*)d_in[16];
    const float* w3 = (const float*)d_in[17];
    const float* g3 = (const float*)d_in[18], *b3 = (const float*)d_in[19];
    const float* m3 = (const float*)d_in[20], *v3 = (const float*)d_in[21];
    const float* w4 = (const float*)d_in[22];
    const float* bias4 = (const float*)d_in[23];

    const int n_sp = in_sizes[2];
    const int N    = in_sizes[6];

    // workspace: [grid NG ints][minc 6][pad to 16B][w16_1|w16_2|w16_3][tvec]
    int* grid = (int*)d_ws;
    int* minc = grid + NG;
    _Float16* w16_1 = (_Float16*)((char*)d_ws + (size_t)(NG + 6) * 4 + 8);
    _Float16* w16_2 = w16_1 + 128 * 192;
    _Float16* w16_3 = w16_2 + 128 * 384;
    float*    tvec  = (float*)(w16_3 + 128 * 384);

    k_init<<<(NG / 4 + 255) / 256, 256, 0, stream>>>((int4*)grid, minc);
    k_scatter<<<(n_sp + 255) / 256, 256, 0, stream>>>(sparse_coords, sparse_batch,
                                                      n_sp, grid, minc);
    k_wconv<<<482, 256, 0, stream>>>(w1, w2, w3,
                                     g1, b1, m1, v1, g2, b2, m2, v2, g3, b3, m3, v3,
                                     w16_1, w16_2, w16_3, tvec);
    k_main<<<(N + PT - 1) / PT, 256, 0, stream>>>(
        pdh, ptsfeat, pts_batch, sparse_feats, grid, minc,
        w16_1, w16_2, w16_3, tvec, w4, bias4, (float*)d_out, N, n_sp);
}